// Round 4
// baseline (440.885 us; speedup 1.0000x reference)
//
#include <hip/hip_runtime.h>
#include <math.h>

// EntmaxBisect, d=4096, alpha=1.5, p=1/4095 (faithful to source).
//
// Collapse (verified absmax 0.0 in R3): every positive term u^p with
// p=1/4095 lies in [0.975, 1), so sum(Z(t)) >= 1 <=> at least 2 elements of
// Xs exceed t <=> second_max(Xs) > t. The 50-iteration bisection is a pure
// scalar binary search toward second_max. Early-exit when
// fl(t_min+diff)==t_min is bit-equivalent to running all 50 iterations.
//
// R4: 8 rows per 256-thread block, register double-buffered. Prefetch row
// r+1 before computing row r. Barriers are hand-rolled
// `s_waitcnt lgkmcnt(0); s_barrier` (LDS-visibility only) so prefetch loads
// and prior-row stores stay in flight across phase boundaries —
// __syncthreads would drain vmcnt(0) and serialize memory against compute.

static constexpr int D    = 4096;
static constexpr int NT   = 256;
static constexpr int ROWS = 8;
static constexpr float P  = (float)(1.0 / 4095.0);   // matches f32(1.0/(d-1))

__device__ __forceinline__ float pow_p(float u) {
#if __has_builtin(__builtin_amdgcn_exp2f) && __has_builtin(__builtin_amdgcn_logf)
    return __builtin_amdgcn_exp2f(P * __builtin_amdgcn_logf(u));
#else
    return exp2f(P * log2f(u));
#endif
}

// Workgroup barrier that only drains LDS (lgkmcnt), NOT vmem — keeps
// prefetch loads / streaming stores outstanding across the barrier.
__device__ __forceinline__ void barrier_lds_only() {
    __asm__ volatile("s_waitcnt lgkmcnt(0)\n\ts_barrier" ::: "memory");
}

__device__ __forceinline__ float wave_sum(float v) {
#pragma unroll
    for (int k = 32; k >= 1; k >>= 1) v += __shfl_xor(v, k, 64);
    return v;
}

__device__ __forceinline__ void top2_merge(float& hi, float& lo, float ohi, float olo) {
    float nhi = fmaxf(hi, ohi);
    float nlo = fmaxf(fminf(hi, ohi), fmaxf(lo, olo));
    hi = nhi; lo = nlo;
}

__global__ void __launch_bounds__(NT) entmax_bisect_kernel(
        const float* __restrict__ X, float* __restrict__ out, int nrows) {
    __shared__ float s_hi[4], s_lo[4], s_sum[4];

    const int tid  = threadIdx.x;
    const int lane = tid & 63;
    const int wid  = tid >> 6;
    const int row0 = blockIdx.x * ROWS;
    const int rows_here = min(ROWS, nrows - row0);

    const float4* Xv = (const float4*)X   + (size_t)row0 * (D / 4);
    float4*       Ov = (float4*)out       + (size_t)row0 * (D / 4);

    float4 cur[4], nxt[4];
    // ---- preload row 0 ----
#pragma unroll
    for (int c = 0; c < 4; ++c) cur[c] = Xv[c * NT + tid];

#pragma unroll
    for (int r = 0; r < ROWS; ++r) {
        if (r >= rows_here) break;
        // ---- prefetch row r+1 (stays in flight through both barriers) ----
        if (r + 1 < rows_here) {
            const float4* Xn = Xv + (size_t)(r + 1) * (D / 4);
#pragma unroll
            for (int c = 0; c < 4; ++c) nxt[c] = Xn[c * NT + tid];
        }

        // ---- Xs = 0.5*X (exact) ----
        float4 xs[4];
#pragma unroll
        for (int c = 0; c < 4; ++c) {
            xs[c].x = 0.5f * cur[c].x; xs[c].y = 0.5f * cur[c].y;
            xs[c].z = 0.5f * cur[c].z; xs[c].w = 0.5f * cur[c].w;
        }

        // ---- per-thread top-2 ----
        float hi = -3.4e38f, lo = -3.4e38f;
#pragma unroll
        for (int c = 0; c < 4; ++c) {
            const float vv[4] = {xs[c].x, xs[c].y, xs[c].z, xs[c].w};
#pragma unroll
            for (int j = 0; j < 4; ++j) {
                float v = vv[j];
                if (v > hi) { lo = hi; hi = v; }
                else        { lo = fmaxf(lo, v); }
            }
        }
        // ---- wave top-2 (butterfly pair-merge) ----
#pragma unroll
        for (int k = 32; k >= 1; k >>= 1) {
            float ohi = __shfl_xor(hi, k, 64);
            float olo = __shfl_xor(lo, k, 64);
            top2_merge(hi, lo, ohi, olo);
        }
        if (lane == 0) { s_hi[wid] = hi; s_lo[wid] = lo; }
        barrier_lds_only();
        float m = s_hi[0], s2 = s_lo[0];
#pragma unroll
        for (int w = 1; w < 4; ++w) top2_merge(m, s2, s_hi[w], s_lo[w]);

        // ---- scalar bisection, redundant on every thread (wave-uniform) ----
        float t_min = m - 1.0f;
        float diff  = (m - 0.015625f) - t_min;   // t_max - t_min, f32 as ref
        float t     = t_min;
#pragma unroll 1
        for (int it = 0; it < 50; ++it) {
            diff *= 0.5f;                  // exact
            t = t_min + diff;
            if (t == t_min) break;         // remaining iterations are no-ops
            if (t < s2) t_min = t;         // == (sum(Z(t)) - 1 >= 0)
        }

        // ---- sum of Z at last probed t (ref: Z = zfun(t) from last iter) ----
        float local = 0.0f;
#pragma unroll
        for (int c = 0; c < 4; ++c) {
            const float vv[4] = {xs[c].x, xs[c].y, xs[c].z, xs[c].w};
#pragma unroll
            for (int j = 0; j < 4; ++j) {
                float u = vv[j] - t;
                if (u > 0.0f) local += pow_p(u);
            }
        }
        local = wave_sum(local);
        if (lane == 0) s_sum[wid] = local;
        barrier_lds_only();
        const float rsum = 1.0f / (s_sum[0] + s_sum[1] + s_sum[2] + s_sum[3]);

        // ---- epilogue: Z(t)/sum, coalesced float4 stores ----
        float4* Or = Ov + (size_t)r * (D / 4);
#pragma unroll
        for (int c = 0; c < 4; ++c) {
            float4 o; float u;
            u = xs[c].x - t; o.x = (u > 0.0f) ? pow_p(u) * rsum : 0.0f;
            u = xs[c].y - t; o.y = (u > 0.0f) ? pow_p(u) * rsum : 0.0f;
            u = xs[c].z - t; o.z = (u > 0.0f) ? pow_p(u) * rsum : 0.0f;
            u = xs[c].w - t; o.w = (u > 0.0f) ? pow_p(u) * rsum : 0.0f;
            Or[c * NT + tid] = o;
        }

        // ---- rotate buffers (compiler renames regs under full unroll) ----
#pragma unroll
        for (int c = 0; c < 4; ++c) cur[c] = nxt[c];
    }
}

extern "C" void kernel_launch(void* const* d_in, const int* in_sizes, int n_in,
                              void* d_out, int out_size, void* d_ws, size_t ws_size,
                              hipStream_t stream) {
    const float* X = (const float*)d_in[0];
    float* O = (float*)d_out;
    const int nrows = in_sizes[0] / D;
    const int nblocks = (nrows + ROWS - 1) / ROWS;
    hipLaunchKernelGGL(entmax_bisect_kernel, dim3(nblocks), dim3(NT), 0, stream,
                       X, O, nrows);
}